// Round 4
// baseline (136.276 us; speedup 1.0000x reference)
//
#include <hip/hip_runtime.h>

// IndexedLinear: out[z, s*V:(s+1)*V] = coeff[s] * x[z, s*U:(s+1)*U] @ W[seg(z), s]
// S=8, U=V=32, C=32 segments, Z=65536. HBM-bound: ~134 MiB -> ~21us @ 6.3TB/s.
// R4: LDS-free, barrier-free bf16-MFMA design.
//  - 1 wave = one 32z x 32v output tile for one s. 16384 tiles, 4 waves/block.
//  - A (x rows) loaded straight from global in MFMA A-layout
//    (m=lane&31, k=8*(lane>>5)+j): 4x dwordx4/lane, each 128-B row window
//    fully covered by the wave. No transpose, no LDS.
//  - B (W cols, coeff folded) via 16 coalesced scalar loads (L2-hot, W=1MiB).
//  - 2x v_mfma_f32_32x32x16_bf16 (K=16 each) -> f32x16 acc.
//  - C/D layout (m74/m101): col=lane&31, row=(reg&3)+8*(reg>>2)+4*(lane>>5);
//    each per-reg store = 2 full 128-B lines (clean writes).
//  - segment via per-wave shfl prefix-scan + ballot; uniform-tile fast path,
//    scalar fallback for tiles crossing a segment boundary (rare/never).

constexpr int S = 8, U = 32, V = 32, C = 32, Z = 65536;
constexpr int SU = S * U;   // 256
constexpr int SV = S * V;   // 256
constexpr int NT = 256;     // 4 waves/block

typedef float  f4    __attribute__((ext_vector_type(4)));
typedef float  f32x16 __attribute__((ext_vector_type(16)));
typedef short  bf16x8 __attribute__((ext_vector_type(8)));

__device__ __forceinline__ short f2bf(float f) {
  // round-to-nearest-even f32 -> bf16 bits
  unsigned u = __builtin_bit_cast(unsigned, f);
  u = (u + 0x7FFFu + ((u >> 16) & 1u)) >> 16;
  return (short)u;
}

__global__ __launch_bounds__(NT) void IndexedLinear_kernel(
    const float* __restrict__ W_all,   // (C, S*U*V)
    const float* __restrict__ X,       // (Z, S*U)
    const int*   __restrict__ counts,  // (C,)
    const float* __restrict__ coeff,   // (S,)
    float*       __restrict__ out)     // (Z, S*V)
{
  const int lane = threadIdx.x & 63;
  const int g    = blockIdx.x * (NT / 64) + (threadIdx.x >> 6);  // tile id
  const int s    = g & 7;
  const int z0   = (g >> 3) * 32;

  const int m = lane & 31;    // A row / B col / C col
  const int h = lane >> 5;    // k-half selector

  // ---- issue A loads first: x[z0+m][u] for u in [8h,8h+8) and [16+8h,+8) ----
  const float* xr = X + (size_t)(z0 + m) * SU + s * U;
  f4 xa = __builtin_nontemporal_load((const f4*)(xr + 8 * h));
  f4 xb = __builtin_nontemporal_load((const f4*)(xr + 8 * h + 4));
  f4 xc = __builtin_nontemporal_load((const f4*)(xr + 16 + 8 * h));
  f4 xd = __builtin_nontemporal_load((const f4*)(xr + 16 + 8 * h + 4));

  // ---- per-wave prefix scan of counts -> segment + uniformity ----
  int c = (lane < C) ? counts[lane] : 0;
  int inc = c;
  #pragma unroll
  for (int d = 1; d < 32; d <<= 1) {
    int o = __shfl_up(inc, d, 64);
    if (lane >= d) inc += o;
  }
  const int exc = inc - c;  // exclusive prefix (valid for lane < C)
  const unsigned long long ma = __ballot(lane < C && exc <= z0);
  const unsigned long long mb = __ballot(lane < C && exc <= z0 + 31);
  const int segA = __popcll(ma) - 1;
  const int segB = __popcll(mb) - 1;

  const float cs = coeff[s];

  if (segA == segB) {
    // ---- fast path: whole tile in one segment ----
    const float* wb = W_all + (size_t)segA * (S * U * V) + s * (U * V);

    // B fragments: b1[j] = cs*W[8h+j][m], b2[j] = cs*W[16+8h+j][m]
    bf16x8 b1, b2;
    #pragma unroll
    for (int j = 0; j < 8; ++j)
      b1[j] = f2bf(wb[(8 * h + j) * V + m] * cs);
    #pragma unroll
    for (int j = 0; j < 8; ++j)
      b2[j] = f2bf(wb[(16 + 8 * h + j) * V + m] * cs);

    // A fragments from the loaded row slices
    bf16x8 a1, a2;
    #pragma unroll
    for (int i = 0; i < 4; ++i) {
      a1[i]     = f2bf(xa[i]);
      a1[4 + i] = f2bf(xb[i]);
      a2[i]     = f2bf(xc[i]);
      a2[4 + i] = f2bf(xd[i]);
    }

    f32x16 acc = {};
    acc = __builtin_amdgcn_mfma_f32_32x32x16_bf16(a1, b1, acc, 0, 0, 0);
    acc = __builtin_amdgcn_mfma_f32_32x32x16_bf16(a2, b2, acc, 0, 0, 0);

    // ---- store: reg -> row=(reg&3)+8*(reg>>2)+4h, col=m ----
    float* ob = out + (size_t)z0 * SV + s * V + m;
    #pragma unroll
    for (int r = 0; r < 16; ++r) {
      const int row = (r & 3) + 8 * (r >> 2) + 4 * h;
      __builtin_nontemporal_store(acc[r], ob + (size_t)row * SV);
    }
  } else {
    // ---- fallback: tile crosses a segment boundary (rare) ----
    // lane handles row z0+m, v range [16h, 16h+16)
    const int zz = z0 + m;
    int sg = 0;
    #pragma unroll 1
    for (int i = 1; i < C; ++i) {
      const int pi = __shfl(exc, i, 64);
      if (pi <= zz) sg = i;
    }
    const float* wr = W_all + (size_t)sg * (S * U * V) + s * (U * V) + 16 * h;
    const float* xrow = X + (size_t)zz * SU + s * U;
    float accv[16] = {};
    #pragma unroll 1
    for (int u = 0; u < U; ++u) {
      const float xu = xrow[u];
      #pragma unroll
      for (int j = 0; j < 16; ++j) accv[j] += xu * wr[u * V + j];
    }
    float* ob = out + (size_t)zz * SV + s * V + 16 * h;
    #pragma unroll
    for (int j = 0; j < 16; ++j) ob[j] = accv[j] * cs;
  }
}

extern "C" void kernel_launch(void* const* d_in, const int* in_sizes, int n_in,
                              void* d_out, int out_size, void* d_ws, size_t ws_size,
                              hipStream_t stream) {
  const float* input1       = (const float*)d_in[0];  // (C, S*U*V)
  const float* input2       = (const float*)d_in[1];  // (Z, S*U)
  const int*   counts       = (const int*)d_in[2];    // (C,)
  const float* coefficients = (const float*)d_in[3];  // (S,)
  float*       out          = (float*)d_out;          // (Z, S*V)

  const int tiles = (Z / 32) * S;        // 16384
  const int grid  = tiles / (NT / 64);   // 4096 blocks
  IndexedLinear_kernel<<<grid, NT, 0, stream>>>(input1, input2, counts,
                                                coefficients, out);
}

// Round 5
// 117.898 us; speedup vs baseline: 1.1559x; 1.1559x over previous
//
#include <hip/hip_runtime.h>

// IndexedLinear: out[z, s*V:(s+1)*V] = coeff[s] * x[z, s*U:(s+1)*U] @ W[seg(z), s]
// S=8, U=V=32, C=32 segments, Z=65536. HBM-bound: ~129 MiB -> ~21us @ 6.3TB/s.
// R5: MFMA + coalesced direct-to-LDS staging (fixes R4's uncoalesced A gather).
//  - block = 4 waves = 32 z x ALL 8 s. X rows contiguous 1KiB -> staged via
//    global_load_lds width=16: 8 instr/wave, 8 full 128B segments per instr.
//  - LDS stores the DMA lane order; xidx(row,chunk) recovers logical (z,u16B):
//    stage iter (w,k), lane i -> slot (8w+k)*64+i holds row 8w+(i&7),
//    chunk 8k+(i>>3)  =>  xidx(r,c) = (r>>3)*512 + (c>>3)*64 + (c&7)*8 + (r&7).
//  - wave w computes s-tiles {2w, 2w+1}: B = 16 coalesced loads (L2-hot, coeff
//    folded into bf16 convert), 2x v_mfma_f32_32x32x16_bf16, verified C/D
//    store map (each per-reg store = 2 full 128-B lines).
//  - one barrier/block; segment via per-wave shfl scan + ballot (overlapped
//    with DMA); uniform fast path, fp32 fallback for boundary blocks.

constexpr int S = 8, U = 32, V = 32, C = 32, Z = 65536;
constexpr int SU = S * U;   // 256
constexpr int SV = S * V;   // 256
constexpr int NT = 256;     // 4 waves
constexpr int BZ = 32;      // z rows per block

typedef float  f4     __attribute__((ext_vector_type(4)));
typedef float  f32x16 __attribute__((ext_vector_type(16)));
typedef short  bf16x8 __attribute__((ext_vector_type(8)));

typedef const __attribute__((address_space(1))) unsigned gu32;
typedef __attribute__((address_space(3))) unsigned lu32;

__device__ __forceinline__ short f2bf(float f) {
  unsigned u = __builtin_bit_cast(unsigned, f);
  u = (u + 0x7FFFu + ((u >> 16) & 1u)) >> 16;
  return (short)u;
}

// LDS f4-slot of logical (row m in [0,32), 16B-chunk c in [0,64))
__device__ __forceinline__ int xidx(int m, int c) {
  return ((m >> 3) << 9) + ((c >> 3) << 6) + ((c & 7) << 3) + (m & 7);
}

__global__ __launch_bounds__(NT) void IndexedLinear_kernel(
    const float* __restrict__ W_all,   // (C, S*U*V)
    const float* __restrict__ X,       // (Z, S*U)
    const int*   __restrict__ counts,  // (C,)
    const float* __restrict__ coeff,   // (S,)
    float*       __restrict__ out)     // (Z, S*V)
{
  const int tid  = threadIdx.x;
  const int lane = tid & 63;
  const int w    = tid >> 6;
  const int z0   = blockIdx.x * BZ;

  __shared__ f4 XL[BZ * 64];  // 32 KiB

  // ---- async stage: 8x global_load_lds (dwordx4) per wave ----
  {
    const char* gbase = (const char*)X
        + (size_t)(z0 + 8 * w + (lane & 7)) * (SU * 4) + (lane >> 3) * 16;
    #pragma unroll
    for (int k = 0; k < 8; ++k) {
      const char* gp = gbase + k * 128;                 // chunk 8k+(lane>>3)
      f4* lp = XL + (8 * w + k) * 64;                   // + lane*16 by HW
      __builtin_amdgcn_global_load_lds((gu32*)gp, (lu32*)lp, 16, 0, 0);
    }
  }

  // ---- per-wave segment scan (overlaps DMA) ----
  int cnt = (lane < C) ? counts[lane] : 0;
  int inc = cnt;
  #pragma unroll
  for (int d = 1; d < 32; d <<= 1) {
    int o = __shfl_up(inc, d, 64);
    if (lane >= d) inc += o;
  }
  const int exc = inc - cnt;
  const unsigned long long ma = __ballot(lane < C && exc <= z0);
  const unsigned long long mb = __ballot(lane < C && exc <= z0 + BZ - 1);
  const int segA = __popcll(ma) - 1;
  const int segB = __popcll(mb) - 1;
  const bool uni = (segA == segB);

  const int m = lane & 31;   // A row / B col / C col
  const int h = lane >> 5;   // k-half
  const int s0 = 2 * w;

  // ---- B fragments for both s-tiles (before barrier; only if uniform) ----
  bf16x8 b1[2], b2[2];
  if (uni) {
    const float* wseg = W_all + (size_t)segA * (S * U * V);
    #pragma unroll
    for (int t = 0; t < 2; ++t) {
      const int s = s0 + t;
      const float cs = coeff[s];
      const float* wb = wseg + s * (U * V);
      #pragma unroll
      for (int j = 0; j < 8; ++j)
        b1[t][j] = f2bf(wb[(8 * h + j) * V + m] * cs);
      #pragma unroll
      for (int j = 0; j < 8; ++j)
        b2[t][j] = f2bf(wb[(16 + 8 * h + j) * V + m] * cs);
    }
  }

  __syncthreads();  // drains DMA (vmcnt) + barrier

  if (uni) {
    #pragma unroll
    for (int t = 0; t < 2; ++t) {
      const int s = s0 + t;
      // A fragments from swizzled LDS (4x ds_read_b128)
      const f4 xa = XL[xidx(m, s * 8 + 2 * h)];
      const f4 xb = XL[xidx(m, s * 8 + 2 * h + 1)];
      const f4 xc = XL[xidx(m, s * 8 + 4 + 2 * h)];
      const f4 xd = XL[xidx(m, s * 8 + 4 + 2 * h + 1)];
      bf16x8 a1, a2;
      #pragma unroll
      for (int i = 0; i < 4; ++i) {
        a1[i]     = f2bf(xa[i]);
        a1[4 + i] = f2bf(xb[i]);
        a2[i]     = f2bf(xc[i]);
        a2[4 + i] = f2bf(xd[i]);
      }
      f32x16 acc = {};
      acc = __builtin_amdgcn_mfma_f32_32x32x16_bf16(a1, b1[t], acc, 0, 0, 0);
      acc = __builtin_amdgcn_mfma_f32_32x32x16_bf16(a2, b2[t], acc, 0, 0, 0);

      float* ob = out + (size_t)z0 * SV + s * V + m;
      #pragma unroll
      for (int r = 0; r < 16; ++r) {
        const int row = (r & 3) + 8 * (r >> 2) + 4 * h;
        __builtin_nontemporal_store(acc[r], ob + (size_t)row * SV);
      }
    }
  } else {
    // ---- fallback: block crosses a segment boundary (fp32 exact) ----
    const int zz = z0 + m;
    int sg = 0;
    #pragma unroll 1
    for (int i = 1; i < C; ++i) {
      const int pi = __shfl(exc, i, 64);
      if (pi <= zz) sg = i;
    }
    #pragma unroll 1
    for (int t = 0; t < 2; ++t) {
      const int s = s0 + t;
      const float cs = coeff[s];
      const float* wr = W_all + (size_t)sg * (S * U * V) + s * (U * V) + 16 * h;
      float accv[16] = {};
      #pragma unroll 1
      for (int cq = 0; cq < 8; ++cq) {
        const f4 xv = XL[xidx(m, s * 8 + cq)];
        #pragma unroll
        for (int ii = 0; ii < 4; ++ii) {
          const int u = cq * 4 + ii;
          const float xu = xv[ii];
          #pragma unroll
          for (int j = 0; j < 16; ++j) accv[j] += xu * wr[u * V + j];
        }
      }
      float* ob = out + (size_t)zz * SV + s * V + 16 * h;
      #pragma unroll
      for (int j = 0; j < 16; ++j) ob[j] = accv[j] * cs;
    }
  }
}

extern "C" void kernel_launch(void* const* d_in, const int* in_sizes, int n_in,
                              void* d_out, int out_size, void* d_ws, size_t ws_size,
                              hipStream_t stream) {
  const float* input1       = (const float*)d_in[0];  // (C, S*U*V)
  const float* input2       = (const float*)d_in[1];  // (Z, S*U)
  const int*   counts       = (const int*)d_in[2];    // (C,)
  const float* coefficients = (const float*)d_in[3];  // (S,)
  float*       out          = (float*)d_out;          // (Z, S*V)

  const int grid = Z / BZ;  // 2048 blocks, each covers all 8 s
  IndexedLinear_kernel<<<grid, NT, 0, stream>>>(input1, input2, counts,
                                                coefficients, out);
}